// Round 3
// baseline (99.191 us; speedup 1.0000x reference)
//
#include <hip/hip_runtime.h>
#include <float.h>

// NearestCluster: per-batch NN argmin.
// coords1 [L1=4096, N=8, C=3] f32 (reference), coords2 [L2=4096, N=8, C=3] f32 (query)
// out int32: [L2*N] argmin idx over L1 per batch, then [L2*N] batch idx.
//
// Numerics: bit-exact vs numpy f32 reference:
//   qq = (q0*q0 + q1*q1) + q2*q2         rr likewise (round each op, no fma)
//   dot = ((q0*r0) + (q1*r1)) + (q2*r2)
//   d2 = (qq + rr) - 2*dot  ==  fma(-2, dot, qq+rr)   (2*dot exact)
// v_pk_*_f32 rounds each half identically to scalar -> packing is exact.
// Ties -> lowest index (np.argmin first occurrence).
//
// R3 post-mortem: occupancy 9->16 waves/CU changed nothing; VALUBusy pinned 63%.
// VALU-busy time (~27.6us) is ~2.2x the packed-math estimate -> compiler
// scalarized the v2f ops. R4: (a) inline-asm VOP3P packed f32 math with op_sel
// broadcasts (3.5 slots/dist, deterministic), (b) 4-ref min-tournament per lane
// so argmin tracking costs ~1.2 slots/dist (index k recovered in epilogue by
// exact recompute; k in low bits of j keeps tie order exact), (c) refs[4][256]
// transposed LDS (conflict-free reads+writes), dwordx3 staging loads.

typedef float v2f __attribute__((ext_vector_type(2)));

constexpr int kL1 = 4096, kL2 = 4096, kN = 8;
constexpr int kChunk = 1024;      // refs per LDS chunk -> 16 KB
constexpr int kQPerBlock = 16;    // 4 waves x 4 queries
constexpr int kQ = 4;             // queries per wave

// d2 for a query PAIR (packed) vs one ref held as r01={rx,ry}, r23={rz,rr}.
// op_sel:[0,x] op_sel_hi:[1,x] -> src0 normal; src1 broadcasts lo (x=0) / hi (x=1).
__device__ __forceinline__ v2f dist_pk(v2f qx, v2f qy, v2f qz, v2f qq,
                                       v2f r01, v2f r23, v2f n2) {
  v2f d, t;
  asm("v_pk_mul_f32 %0, %2, %6 op_sel:[0,0] op_sel_hi:[1,0]\n\t"  // qx*rx
      "v_pk_mul_f32 %1, %3, %6 op_sel:[0,1] op_sel_hi:[1,1]\n\t"  // qy*ry
      "v_pk_add_f32 %0, %0, %1\n\t"                               // s01
      "v_pk_mul_f32 %1, %4, %7 op_sel:[0,0] op_sel_hi:[1,0]\n\t"  // qz*rz
      "v_pk_add_f32 %0, %0, %1\n\t"                               // dot
      "v_pk_add_f32 %1, %5, %7 op_sel:[0,1] op_sel_hi:[1,1]\n\t"  // A = qq+rr
      "v_pk_fma_f32 %0, %0, %8, %1"                               // A - 2*dot
      : "=&v"(d), "=&v"(t)
      : "v"(qx), "v"(qy), "v"(qz), "v"(qq), "v"(r01), "v"(r23), "v"(n2));
  return d;
}

__global__ __launch_bounds__(256, 4)
void nearest_kernel(const float* __restrict__ c1, const float* __restrict__ c2,
                    int* __restrict__ out) {
#pragma clang fp contract(off)
  __shared__ float4 refs[4][256];  // [k][w]: ref j = chunkbase + w*4 + k

  const int tid = threadIdx.x;
  const int n = blockIdx.y;
  const int wave = tid >> 6;
  const int lane = tid & 63;
  const int q0 = blockIdx.x * kQPerBlock + wave * kQ;

  float qxs[kQ], qys[kQ], qzs[kQ], qqs[kQ];
#pragma unroll
  for (int i = 0; i < kQ; ++i) {
    const float* p = c2 + ((q0 + i) * kN + n) * 3;
    qxs[i] = p[0]; qys[i] = p[1]; qzs[i] = p[2];
    qqs[i] = __fadd_rn(__fadd_rn(__fmul_rn(qxs[i], qxs[i]), __fmul_rn(qys[i], qys[i])),
                       __fmul_rn(qzs[i], qzs[i]));
  }
  const v2f qx01 = {qxs[0], qxs[1]}, qx23 = {qxs[2], qxs[3]};
  const v2f qy01 = {qys[0], qys[1]}, qy23 = {qys[2], qys[3]};
  const v2f qz01 = {qzs[0], qzs[1]}, qz23 = {qzs[2], qzs[3]};
  const v2f qq01 = {qqs[0], qqs[1]}, qq23 = {qqs[2], qqs[3]};
  const v2f n2 = {-2.0f, -2.0f};

  float bd[kQ]; int bt[kQ];
#pragma unroll
  for (int i = 0; i < kQ; ++i) { bd[i] = FLT_MAX; bt[i] = 0; }

  int tg = 0;  // global t counter; candidate j = (tg*64+lane)*4 + k
  for (int chunk = 0; chunk < kL1 / kChunk; ++chunk) {
    __syncthreads();  // previous chunk's readers done before overwrite

    // ---- Stage: thread w handles 4 consecutive refs w*4+k -> refs[k][w].
    //      Writes conflict-free (lanes consecutive per k). dwordx3 loads.
    {
      const int jb = chunk * kChunk + tid * 4;
#pragma unroll
      for (int k = 0; k < 4; ++k) {
        const float3 rp = *reinterpret_cast<const float3*>(c1 + ((jb + k) * kN + n) * 3);
        const float rr = __fadd_rn(
            __fadd_rn(__fmul_rn(rp.x, rp.x), __fmul_rn(rp.y, rp.y)),
            __fmul_rn(rp.z, rp.z));
        refs[k][tid] = make_float4(rp.x, rp.y, rp.z, rr);
      }
    }
    __syncthreads();

#pragma unroll
    for (int t = 0; t < kChunk / 256; ++t, ++tg) {  // 4 iters/chunk, 256 refs/iter
      const float4 rA = refs[0][t * 64 + lane];
      const float4 rB = refs[1][t * 64 + lane];
      const float4 rC = refs[2][t * 64 + lane];
      const float4 rD = refs[3][t * 64 + lane];

      const v2f dA01 = dist_pk(qx01, qy01, qz01, qq01, (v2f){rA.x, rA.y}, (v2f){rA.z, rA.w}, n2);
      const v2f dA23 = dist_pk(qx23, qy23, qz23, qq23, (v2f){rA.x, rA.y}, (v2f){rA.z, rA.w}, n2);
      const v2f dB01 = dist_pk(qx01, qy01, qz01, qq01, (v2f){rB.x, rB.y}, (v2f){rB.z, rB.w}, n2);
      const v2f dB23 = dist_pk(qx23, qy23, qz23, qq23, (v2f){rB.x, rB.y}, (v2f){rB.z, rB.w}, n2);
      const v2f dC01 = dist_pk(qx01, qy01, qz01, qq01, (v2f){rC.x, rC.y}, (v2f){rC.z, rC.w}, n2);
      const v2f dC23 = dist_pk(qx23, qy23, qz23, qq23, (v2f){rC.x, rC.y}, (v2f){rC.z, rC.w}, n2);
      const v2f dD01 = dist_pk(qx01, qy01, qz01, qq01, (v2f){rD.x, rD.y}, (v2f){rD.z, rD.w}, n2);
      const v2f dD23 = dist_pk(qx23, qy23, qz23, qq23, (v2f){rD.x, rD.y}, (v2f){rD.z, rD.w}, n2);

      // min-tournament over the 4 k-candidates per query; track tg only.
      const float m0 = fminf(fminf(dA01.x, dB01.x), fminf(dC01.x, dD01.x));
      const float m1 = fminf(fminf(dA01.y, dB01.y), fminf(dC01.y, dD01.y));
      const float m2 = fminf(fminf(dA23.x, dB23.x), fminf(dC23.x, dD23.x));
      const float m3 = fminf(fminf(dA23.y, dB23.y), fminf(dC23.y, dD23.y));
      if (m0 < bd[0]) { bd[0] = m0; bt[0] = tg; }
      if (m1 < bd[1]) { bd[1] = m1; bt[1] = tg; }
      if (m2 < bd[2]) { bd[2] = m2; bt[2] = tg; }
      if (m3 < bd[3]) { bd[3] = m3; bt[3] = tg; }
    }
  }

  // ---- Cross-lane merge on (d, sel) with sel = bt*64+lane. Since candidate
  //      j = sel*4 + k, ordering by sel is exact first-occurrence ordering.
  int sel[kQ];
#pragma unroll
  for (int i = 0; i < kQ; ++i) sel[i] = bt[i] * 64 + lane;
#pragma unroll
  for (int m = 1; m <= 32; m <<= 1) {
#pragma unroll
    for (int i = 0; i < kQ; ++i) {
      const float od = __shfl_xor(bd[i], m);
      const int os = __shfl_xor(sel[i], m);
      if (od < bd[i] || (od == bd[i] && os < sel[i])) { bd[i] = od; sel[i] = os; }
    }
  }

  // ---- Epilogue: resolve k by exact recompute of the 4 winning candidates.
  //      lane i (< kQ) handles query i; all indices compile-time (no scratch).
#pragma unroll
  for (int i = 0; i < kQ; ++i) {
    if (lane == i) {
      const int j0 = sel[i] * 4;
      float dc[4];
#pragma unroll
      for (int k = 0; k < 4; ++k) {
        const float3 rp = *reinterpret_cast<const float3*>(c1 + ((j0 + k) * kN + n) * 3);
        const float rr = __fadd_rn(
            __fadd_rn(__fmul_rn(rp.x, rp.x), __fmul_rn(rp.y, rp.y)),
            __fmul_rn(rp.z, rp.z));
        const float dot = __fadd_rn(
            __fadd_rn(__fmul_rn(qxs[i], rp.x), __fmul_rn(qys[i], rp.y)),
            __fmul_rn(qzs[i], rp.z));
        dc[k] = __fmaf_rn(-2.0f, dot, __fadd_rn(qqs[i], rr));
      }
      int kk = 3;
      if (dc[2] == bd[i]) kk = 2;
      if (dc[1] == bd[i]) kk = 1;
      if (dc[0] == bd[i]) kk = 0;
      out[(q0 + i) * kN + n] = j0 + kk;
      out[kL2 * kN + (q0 + i) * kN + n] = n;
    }
  }
}

extern "C" void kernel_launch(void* const* d_in, const int* in_sizes, int n_in,
                              void* d_out, int out_size, void* d_ws, size_t ws_size,
                              hipStream_t stream) {
  const float* c1 = (const float*)d_in[0];
  const float* c2 = (const float*)d_in[1];
  int* out = (int*)d_out;
  dim3 grid(kL2 / kQPerBlock, kN);  // 256 x 8 = 2048 blocks
  nearest_kernel<<<grid, dim3(256), 0, stream>>>(c1, c2, out);
}